// Round 1
// baseline (794.426 us; speedup 1.0000x reference)
//
#include <hip/hip_runtime.h>
#include <hip/hip_bf16.h>

// RGCN segment MM: out[d] = sum_{e: dst[e]==d} feat[src[e]] @ W[etype[e]]
// N=100000 nodes, E=1.6M edges, R=8 relations, 128->128 features, fp32 I/O.
//
// Strategy: counting-sort edges by etype (buckets padded to 128), then each
// 128-edge chunk does a single-relation 128x128x128 bf16 MFMA GEMM with
// gathered feat rows, scattering results with native fp32 atomics.

#define FEAT 128
#define TM 128              // edges per chunk
#define LDK 136             // padded LDS stride (bf16 elems), keeps 16B align
#define EPB 2048            // edges per scatter block
#define NREL_MAX 8

typedef __attribute__((ext_vector_type(8))) short short8;
typedef __attribute__((ext_vector_type(8))) __bf16 bf16x8;
typedef __attribute__((ext_vector_type(4))) float f32x4;

__device__ __forceinline__ ushort f2bf(float x) {
    union { float f; unsigned int u; } v; v.f = x;
    unsigned int r = v.u + 0x7FFFu + ((v.u >> 16) & 1u);   // RNE
    return (ushort)(r >> 16);
}

// ---------------- conversion kernels ----------------
__global__ void cvt_feat_kernel(const float* __restrict__ f,
                                ushort* __restrict__ o, int n8) {
    int i = blockIdx.x * blockDim.x + threadIdx.x;
    if (i >= n8) return;
    const float4* f4 = (const float4*)f;
    float4 a = f4[2 * i], b = f4[2 * i + 1];
    union { ushort u[8]; int4 v; } pk;
    pk.u[0] = f2bf(a.x); pk.u[1] = f2bf(a.y); pk.u[2] = f2bf(a.z); pk.u[3] = f2bf(a.w);
    pk.u[4] = f2bf(b.x); pk.u[5] = f2bf(b.y); pk.u[6] = f2bf(b.z); pk.u[7] = f2bf(b.w);
    ((int4*)o)[i] = pk.v;
}

// W[r][k][n] (fp32) -> Wt[r][n][k] (bf16)
__global__ void cvt_w_kernel(const float* __restrict__ w,
                             ushort* __restrict__ wt, int total) {
    int i = blockIdx.x * blockDim.x + threadIdx.x;
    if (i >= total) return;
    int r = i >> 14;
    int n = (i >> 7) & 127;
    int k = i & 127;
    wt[i] = f2bf(w[(r << 14) + (k << 7) + n]);
}

// ---------------- counting sort by etype ----------------
__global__ void hist_kernel(const int* __restrict__ et, int E,
                            int* __restrict__ counts) {
    __shared__ int h[NREL_MAX];
    if (threadIdx.x < NREL_MAX) h[threadIdx.x] = 0;
    __syncthreads();
    for (int i = blockIdx.x * blockDim.x + threadIdx.x; i < E;
         i += gridDim.x * blockDim.x)
        atomicAdd(&h[et[i]], 1);
    __syncthreads();
    if (threadIdx.x < NREL_MAX) atomicAdd(&counts[threadIdx.x], h[threadIdx.x]);
}

__global__ void scan_kernel(const int* __restrict__ counts,
                            int* __restrict__ poff, int* __restrict__ cursor,
                            int R) {
    if (threadIdx.x == 0 && blockIdx.x == 0) {
        int acc = 0;
        for (int r = 0; r < R; r++) {
            poff[r] = acc;
            cursor[r] = acc;
            acc += ((counts[r] + TM - 1) / TM) * TM;   // pad bucket to TM
        }
        poff[R] = acc;
    }
}

__global__ void scatter_kernel(const int* __restrict__ et, int E,
                               int* __restrict__ cursor,
                               int* __restrict__ sidx) {
    __shared__ int h[NREL_MAX], base[NREL_MAX], cur[NREL_MAX];
    int t = threadIdx.x;
    if (t < NREL_MAX) { h[t] = 0; cur[t] = 0; }
    __syncthreads();
    int start = blockIdx.x * EPB;
    int myet[EPB / 256];
    for (int k = 0; k < EPB / 256; k++) {
        int i = start + k * 256 + t;
        int r = (i < E) ? et[i] : -1;
        myet[k] = r;
        if (r >= 0) atomicAdd(&h[r], 1);
    }
    __syncthreads();
    if (t < NREL_MAX) base[t] = atomicAdd(&cursor[t], h[t]);
    __syncthreads();
    for (int k = 0; k < EPB / 256; k++) {
        int r = myet[k];
        if (r >= 0) {
            int pos = base[r] + atomicAdd(&cur[r], 1);
            sidx[pos] = start + k * 256 + t;
        }
    }
}

// ---------------- main fused GEMM + scatter ----------------
__global__ __launch_bounds__(256, 2)
void rgcn_main_kernel(const ushort* __restrict__ featb,
                      const ushort* __restrict__ wtb,
                      const int* __restrict__ src,
                      const int* __restrict__ dst,
                      const int* __restrict__ sidx,
                      const int* __restrict__ poff,
                      float* __restrict__ out, int R) {
    __shared__ __align__(16) ushort Asm[TM * LDK];   // 34816 B
    __shared__ __align__(16) ushort Bsm[FEAT * LDK]; // 34816 B
    __shared__ int dstArr[TM];
    __shared__ int srcArr[TM];

    int t = threadIdx.x;
    int base = blockIdx.x * TM;
    int total = poff[R];
    if (base >= total) return;

    // which relation does this chunk belong to? (buckets are TM-aligned)
    int r = 0;
    for (int i = 1; i < R; i++)
        if (base >= poff[i]) r = i;

    if (t < TM) {
        int e = sidx[base + t];
        int s = 0, d = -1;
        if (e >= 0) { s = src[e]; d = dst[e]; }
        srcArr[t] = s;
        dstArr[t] = d;
    }
    __syncthreads();

    // stage A (gathered feat rows) and Bt (W[r] transposed) into LDS
    const ushort* wrow = wtb + ((size_t)r << 14);
    for (int i = 0; i < 8; i++) {
        int flat = i * 256 + t;      // 0..2047
        int row = flat >> 4;         // 0..127  (edge row for A, n for B)
        int chunk = flat & 15;       // 16-byte chunk within row
        int s = srcArr[row];
        int4 va = ((const int4*)(featb + (size_t)s * FEAT))[chunk];
        *(int4*)&Asm[row * LDK + chunk * 8] = va;
        int4 vb = ((const int4*)(wrow + row * FEAT))[chunk];
        *(int4*)&Bsm[row * LDK + chunk * 8] = vb;
    }
    __syncthreads();

    int wid = t >> 6, lane = t & 63;
    int mq = (wid >> 1) * 64;
    int nq = (wid & 1) * 64;
    int lm = lane & 15;
    int lq = lane >> 4;

    f32x4 acc[16];
    for (int i = 0; i < 16; i++) acc[i] = (f32x4){0.f, 0.f, 0.f, 0.f};

    for (int kk = 0; kk < 4; kk++) {
        int kof = kk * 32 + lq * 8;
        short8 af[4], bfg[4];
        for (int tm = 0; tm < 4; tm++)
            af[tm] = *(const short8*)&Asm[(mq + tm * 16 + lm) * LDK + kof];
        for (int tn = 0; tn < 4; tn++)
            bfg[tn] = *(const short8*)&Bsm[(nq + tn * 16 + lm) * LDK + kof];
        for (int tm = 0; tm < 4; tm++)
            for (int tn = 0; tn < 4; tn++)
                acc[tm * 4 + tn] = __builtin_amdgcn_mfma_f32_16x16x32_bf16(
                    __builtin_bit_cast(bf16x8, af[tm]),
                    __builtin_bit_cast(bf16x8, bfg[tn]),
                    acc[tm * 4 + tn], 0, 0, 0);
    }

    // epilogue: atomic scatter rows to out[dst]
    for (int tm = 0; tm < 4; tm++) {
        for (int i = 0; i < 4; i++) {
            int row = mq + tm * 16 + lq * 4 + i;
            int d = dstArr[row];
            if (d >= 0) {
                float* op = out + (size_t)d * FEAT + nq + lm;
                for (int tn = 0; tn < 4; tn++)
                    unsafeAtomicAdd(op + tn * 16, acc[tm * 4 + tn][i]);
            }
        }
    }
}

extern "C" void kernel_launch(void* const* d_in, const int* in_sizes, int n_in,
                              void* d_out, int out_size, void* d_ws,
                              size_t ws_size, hipStream_t stream) {
    const float* feat = (const float*)d_in[0];
    const float* weight = (const float*)d_in[1];
    const int* src = (const int*)d_in[2];
    const int* dst = (const int*)d_in[3];
    const int* et = (const int*)d_in[4];

    int nfeat = in_sizes[0];                 // N * 128
    int R = in_sizes[1] / (FEAT * FEAT);     // 8
    int E = in_sizes[2];                     // 1.6M
    float* out = (float*)d_out;

    // workspace layout
    char* ws = (char*)d_ws;
    int* counts = (int*)ws;                  // [8]
    int* cursor = counts + NREL_MAX;         // [8]
    int* poff = cursor + NREL_MAX;           // [9]
    int* sidx = (int*)(ws + 256);            // [E + R*TM]
    size_t sidxBytes = (size_t)(E + R * TM) * sizeof(int);
    size_t off = 256 + ((sidxBytes + 255) & ~(size_t)255);
    ushort* featb = (ushort*)(ws + off);     // [nfeat] bf16
    ushort* wtb = featb + (size_t)nfeat;     // [R*128*128] bf16 transposed

    hipMemsetAsync(counts, 0, 64, stream);
    hipMemsetAsync(sidx, 0xFF, sidxBytes, stream);
    hipMemsetAsync(out, 0, (size_t)out_size * sizeof(float), stream);

    int n8 = nfeat / 8;
    cvt_feat_kernel<<<(n8 + 255) / 256, 256, 0, stream>>>(feat, featb, n8);
    int wtotal = R * FEAT * FEAT;
    cvt_w_kernel<<<(wtotal + 255) / 256, 256, 0, stream>>>(weight, wtb, wtotal);
    hist_kernel<<<512, 256, 0, stream>>>(et, E, counts);
    scan_kernel<<<1, 64, 0, stream>>>(counts, poff, cursor, R);
    scatter_kernel<<<(E + EPB - 1) / EPB, 256, 0, stream>>>(et, E, cursor, sidx);

    int nchunk = (E + TM - 1) / TM + R;
    rgcn_main_kernel<<<nchunk, 256, 0, stream>>>(featb, wtb, src, dst, sidx,
                                                 poff, out, R);
}

// Round 2
// 652.821 us; speedup vs baseline: 1.2169x; 1.2169x over previous
//
#include <hip/hip_runtime.h>
#include <hip/hip_bf16.h>

// RGCN segment MM via aggregate-first:
//   out[d] = sum_r ( sum_{e: dst=d, et=r} feat[src[e]] ) @ W[r]
//           = H[d, :] @ Wstack   with H[d] = concat_r S_r(d), K = R*128.
// Pipeline: counting-sort edges by dst -> per-node segment aggregation into
// bf16 H -> single dense bf16 MFMA GEMM (no atomics anywhere on the output).

#define FEAT 128
#define NRELM 8
#define CNT_PAD 100352     // 98 * 1024, >= N+1
#define SCAN_BLK 1024
#define BKP 64             // phase-2 K chunk
#define LDKB 72            // padded LDS stride (bf16 elems)

typedef __attribute__((ext_vector_type(8))) short short8;
typedef __attribute__((ext_vector_type(8))) __bf16 bf16x8;
typedef __attribute__((ext_vector_type(4))) float f32x4;

__device__ __forceinline__ ushort f2bf(float x) {
    union { float f; unsigned u; } v; v.f = x;
    unsigned r = v.u + 0x7FFFu + ((v.u >> 16) & 1u);   // RNE
    return (ushort)(r >> 16);
}

// ---------------- conversions ----------------
__global__ void cvt_feat_kernel(const float* __restrict__ f,
                                ushort* __restrict__ o, int n8) {
    int i = blockIdx.x * blockDim.x + threadIdx.x;
    if (i >= n8) return;
    const float4* f4 = (const float4*)f;
    float4 a = f4[2 * i], b = f4[2 * i + 1];
    union { ushort u[8]; int4 v; } pk;
    pk.u[0] = f2bf(a.x); pk.u[1] = f2bf(a.y); pk.u[2] = f2bf(a.z); pk.u[3] = f2bf(a.w);
    pk.u[4] = f2bf(b.x); pk.u[5] = f2bf(b.y); pk.u[6] = f2bf(b.z); pk.u[7] = f2bf(b.w);
    ((int4*)o)[i] = pk.v;
}

// W[r][k][n] fp32 -> Wt[n][r*128+k] bf16 (K-stacked, n-major)
__global__ void cvt_w_kernel(const float* __restrict__ w,
                             ushort* __restrict__ wt, int total, int KW) {
    int i = blockIdx.x * blockDim.x + threadIdx.x;
    if (i >= total) return;
    int n = i / KW;
    int rk = i - n * KW;
    int r = rk >> 7, k = rk & 127;
    wt[i] = f2bf(w[(r << 14) + (k << 7) + n]);
}

// ---------------- counting sort by dst ----------------
__global__ void hist_kernel(const int* __restrict__ dst, int E,
                            int* __restrict__ cnt) {
    int i = blockIdx.x * blockDim.x + threadIdx.x;
    int stride = gridDim.x * blockDim.x;
    for (; i < E; i += stride) atomicAdd(&cnt[dst[i]], 1);
}

__global__ void scan1_kernel(const int* __restrict__ cnt, int* __restrict__ bsum) {
    int lane = threadIdx.x;
    int base = blockIdx.x * SCAN_BLK + lane * 16;
    int s = 0;
    for (int i = 0; i < 16; i++) s += cnt[base + i];
    for (int o = 32; o; o >>= 1) s += __shfl_down(s, o, 64);
    if (lane == 0) bsum[blockIdx.x] = s;
}

__global__ void scan2_kernel(int* __restrict__ bsum, int nb) {
    if (threadIdx.x == 0 && blockIdx.x == 0) {
        int run = 0;
        for (int b = 0; b < nb; b++) { int t = bsum[b]; bsum[b] = run; run += t; }
    }
}

__global__ void scan3_kernel(const int* __restrict__ cnt,
                             const int* __restrict__ bsum,
                             int* __restrict__ off, int* __restrict__ cursor) {
    int lane = threadIdx.x;
    int base = blockIdx.x * SCAN_BLK + lane * 16;
    int local[16]; int s = 0;
    #pragma unroll
    for (int i = 0; i < 16; i++) { local[i] = cnt[base + i]; s += local[i]; }
    int x = s;
    for (int o = 1; o < 64; o <<= 1) { int y = __shfl_up(x, o, 64); if (lane >= o) x += y; }
    int run = bsum[blockIdx.x] + x - s;     // exclusive prefix
    #pragma unroll
    for (int i = 0; i < 16; i++) { off[base + i] = run; cursor[base + i] = run; run += local[i]; }
}

__global__ void scatter_kernel(const int* __restrict__ dst, int E,
                               int* __restrict__ cursor, int* __restrict__ sidx) {
    int i = blockIdx.x * blockDim.x + threadIdx.x;
    int stride = gridDim.x * blockDim.x;
    for (; i < E; i += stride) {
        int p = atomicAdd(&cursor[dst[i]], 1);
        sidx[p] = i;
    }
}

// ---------------- phase 1: per-node segment aggregation ----------------
// one wave per dst node; lane covers feat cols {2*lane, 2*lane+1}
__global__ __launch_bounds__(256)
void phase1_kernel(const float* __restrict__ featf,
                   const ushort* __restrict__ featb, int useBf,
                   const int* __restrict__ src, const int* __restrict__ et,
                   const int* __restrict__ sidx, const int* __restrict__ off,
                   ushort* __restrict__ H, int N, int Npad,
                   int rbase, int rcount, int KR) {
    int d = blockIdx.x * 4 + (threadIdx.x >> 6);
    if (d >= Npad) return;
    int lane = threadIdx.x & 63;
    float S[NRELM][2];
    #pragma unroll
    for (int r = 0; r < NRELM; r++) { S[r][0] = 0.f; S[r][1] = 0.f; }

    if (d < N) {
        int beg = off[d], end = off[d + 1];
        for (int j0 = beg; j0 < end; j0 += 64) {
            int cntc = end - j0; if (cntc > 64) cntc = 64;
            int rv = -1, sv = 0;
            if (lane < cntc) {
                int e = sidx[j0 + lane];
                rv = et[e] - rbase;
                sv = src[e];
            }
            for (int jb = 0; jb < cntc; jb += 8) {
                unsigned vlo[8], vhi[8]; int rr[8];
                #pragma unroll
                for (int j = 0; j < 8; j++) {
                    int jj = jb + j; if (jj > 63) jj = 63;
                    int r = __shfl(rv, jj, 64);
                    rr[j] = r;
                    vlo[j] = 0u; vhi[j] = 0u;
                    if ((unsigned)r < (unsigned)rcount) {
                        int s = __shfl(sv, jj, 64);
                        if (useBf) {
                            unsigned v = *(const unsigned*)&featb[(size_t)s * FEAT + 2 * lane];
                            vlo[j] = v << 16;
                            vhi[j] = v & 0xffff0000u;
                        } else {
                            float2 f = *(const float2*)&featf[(size_t)s * FEAT + 2 * lane];
                            vlo[j] = __float_as_uint(f.x);
                            vhi[j] = __float_as_uint(f.y);
                        }
                    }
                }
                #pragma unroll
                for (int j = 0; j < 8; j++) {
                    int r = rr[j];
                    if ((unsigned)r >= (unsigned)rcount) continue;
                    float f0 = __uint_as_float(vlo[j]);
                    float f1 = __uint_as_float(vhi[j]);
                    switch (r) {   // r is wave-uniform -> scalar branch tree
                        case 0: S[0][0] += f0; S[0][1] += f1; break;
                        case 1: S[1][0] += f0; S[1][1] += f1; break;
                        case 2: S[2][0] += f0; S[2][1] += f1; break;
                        case 3: S[3][0] += f0; S[3][1] += f1; break;
                        case 4: S[4][0] += f0; S[4][1] += f1; break;
                        case 5: S[5][0] += f0; S[5][1] += f1; break;
                        case 6: S[6][0] += f0; S[6][1] += f1; break;
                        case 7: S[7][0] += f0; S[7][1] += f1; break;
                    }
                }
            }
        }
    }
    ushort* hrow = H + (size_t)d * KR + 2 * lane;
    #pragma unroll
    for (int r = 0; r < NRELM; r++) {
        if (r >= rcount) break;
        unsigned p = (unsigned)f2bf(S[r][0]) | ((unsigned)f2bf(S[r][1]) << 16);
        *(unsigned*)(hrow + r * FEAT) = p;
    }
}

// ---------------- phase 2: out(+)= H @ Wstack ----------------
__global__ __launch_bounds__(256)
void phase2_kernel(const ushort* __restrict__ H, const ushort* __restrict__ wtb,
                   float* __restrict__ out, int N, int KR, int KW, int kbase,
                   int accum) {
    __shared__ __align__(16) ushort Asm[128 * LDKB];
    __shared__ __align__(16) ushort Bsm[128 * LDKB];
    int t = threadIdx.x;
    int base = blockIdx.x * 128;
    int wid = t >> 6, lane = t & 63;
    int mq = (wid >> 1) * 64, nq = (wid & 1) * 64;
    int lm = lane & 15, lq = lane >> 4;

    f32x4 acc[16];
    #pragma unroll
    for (int i = 0; i < 16; i++) acc[i] = (f32x4){0.f, 0.f, 0.f, 0.f};

    for (int kc = 0; kc < KR; kc += BKP) {
        #pragma unroll
        for (int it = 0; it < 4; it++) {
            int flat = it * 256 + t;          // 0..1023
            int row = flat >> 3, c = flat & 7;
            int4 va = *(const int4*)&H[(size_t)(base + row) * KR + kc + c * 8];
            *(int4*)&Asm[row * LDKB + c * 8] = va;
            int4 vb = *(const int4*)&wtb[(size_t)row * KW + kbase + kc + c * 8];
            *(int4*)&Bsm[row * LDKB + c * 8] = vb;
        }
        __syncthreads();
        #pragma unroll
        for (int ks = 0; ks < 2; ks++) {
            int kof = ks * 32 + lq * 8;
            short8 af[4], bfg[4];
            #pragma unroll
            for (int tm = 0; tm < 4; tm++)
                af[tm] = *(const short8*)&Asm[(mq + tm * 16 + lm) * LDKB + kof];
            #pragma unroll
            for (int tn = 0; tn < 4; tn++)
                bfg[tn] = *(const short8*)&Bsm[(nq + tn * 16 + lm) * LDKB + kof];
            #pragma unroll
            for (int tm = 0; tm < 4; tm++)
                #pragma unroll
                for (int tn = 0; tn < 4; tn++)
                    acc[tm * 4 + tn] = __builtin_amdgcn_mfma_f32_16x16x32_bf16(
                        __builtin_bit_cast(bf16x8, af[tm]),
                        __builtin_bit_cast(bf16x8, bfg[tn]),
                        acc[tm * 4 + tn], 0, 0, 0);
        }
        __syncthreads();
    }

    #pragma unroll
    for (int tm = 0; tm < 4; tm++) {
        #pragma unroll
        for (int i = 0; i < 4; i++) {
            int row = base + mq + tm * 16 + lq * 4 + i;
            if (row < N) {
                float* op = out + (size_t)row * FEAT + nq + lm;
                if (accum) {
                    #pragma unroll
                    for (int tn = 0; tn < 4; tn++) op[tn * 16] += acc[tm * 4 + tn][i];
                } else {
                    #pragma unroll
                    for (int tn = 0; tn < 4; tn++) op[tn * 16] = acc[tm * 4 + tn][i];
                }
            }
        }
    }
}

static inline size_t al256(size_t x) { return (x + 255) & ~(size_t)255; }

extern "C" void kernel_launch(void* const* d_in, const int* in_sizes, int n_in,
                              void* d_out, int out_size, void* d_ws,
                              size_t ws_size, hipStream_t stream) {
    const float* feat = (const float*)d_in[0];
    const float* weight = (const float*)d_in[1];
    const int* src = (const int*)d_in[2];
    const int* dst = (const int*)d_in[3];
    const int* et = (const int*)d_in[4];

    int nfeat = in_sizes[0];
    int N = nfeat / FEAT;                    // 100000
    int R = in_sizes[1] / (FEAT * FEAT);     // 8
    int E = in_sizes[2];                     // 1.6M
    int Npad = ((N + 127) / 128) * 128;      // 100096
    int KW = R * FEAT;                       // 1024
    float* out = (float*)d_out;

    // ---- workspace layout ----
    char* ws = (char*)d_ws;
    size_t o = 0;
    size_t cnt_o  = o; o += al256((size_t)CNT_PAD * 4);
    size_t bsum_o = o; o += al256(256 * 4);
    size_t off_o  = o; o += al256((size_t)(CNT_PAD + 8) * 4);
    size_t cur_o  = o; o += al256((size_t)CNT_PAD * 4);
    size_t sidx_o = o; o += al256((size_t)E * 4);
    size_t wtb_o  = o; o += al256((size_t)R * FEAT * FEAT * 2);
    size_t base_o = o;

    // pick (relation-split, bf16-gather) so the footprint fits ws
    int RS = 8, useBf = 0;
    const int cand_rs[5] = {1, 2, 4, 4, 8};
    const int cand_bf[5] = {1, 1, 1, 0, 0};
    for (int c = 0; c < 5; c++) {
        size_t need = base_o
                    + (cand_bf[c] ? al256((size_t)nfeat * 2) : 0)
                    + al256((size_t)Npad * (size_t)(KW / cand_rs[c]) * 2);
        if (need <= ws_size) { RS = cand_rs[c]; useBf = cand_bf[c]; break; }
    }
    int RC = R / RS;                         // relations per pass
    int KR = RC * FEAT;                      // K per pass
    size_t featb_o = base_o;
    size_t H_o = base_o + (useBf ? al256((size_t)nfeat * 2) : 0);

    int* cnt    = (int*)(ws + cnt_o);
    int* bsum   = (int*)(ws + bsum_o);
    int* off    = (int*)(ws + off_o);
    int* cursor = (int*)(ws + cur_o);
    int* sidx   = (int*)(ws + sidx_o);
    ushort* wtb   = (ushort*)(ws + wtb_o);
    ushort* featb = (ushort*)(ws + featb_o);
    ushort* H     = (ushort*)(ws + H_o);

    hipMemsetAsync(cnt, 0, (size_t)CNT_PAD * 4, stream);

    int wtotal = R * FEAT * FEAT;
    cvt_w_kernel<<<(wtotal + 255) / 256, 256, 0, stream>>>(weight, wtb, wtotal, KW);
    if (useBf) {
        int n8 = nfeat / 8;
        cvt_feat_kernel<<<(n8 + 255) / 256, 256, 0, stream>>>(feat, featb, n8);
    }
    hist_kernel<<<512, 256, 0, stream>>>(dst, E, cnt);
    int nb = CNT_PAD / SCAN_BLK;             // 98
    scan1_kernel<<<nb, 64, 0, stream>>>(cnt, bsum);
    scan2_kernel<<<1, 64, 0, stream>>>(bsum, nb);
    scan3_kernel<<<nb, 64, 0, stream>>>(cnt, bsum, off, cursor);
    scatter_kernel<<<512, 256, 0, stream>>>(dst, E, cursor, sidx);

    for (int p = 0; p < RS; p++) {
        phase1_kernel<<<Npad / 4, 256, 0, stream>>>(
            feat, featb, useBf, src, et, sidx, off, H, N, Npad,
            p * RC, RC, KR);
        phase2_kernel<<<Npad / 128, 256, 0, stream>>>(
            H, wtb, out, N, KR, KW, p * KR, p > 0 ? 1 : 0);
    }
}

// Round 3
// 591.579 us; speedup vs baseline: 1.3429x; 1.1035x over previous
//
#include <hip/hip_runtime.h>
#include <hip/hip_bf16.h>

// RGCN segment MM via aggregate-first:
//   out[d] = sum_r ( sum_{e: dst=d, et=r} feat[src[e]] ) @ W[r]
// Pipeline: counting-sort edges by key = dst*R + et (sidx stores SRC node id,
// so phase1 touches no per-edge arrays except the sorted one) -> per-node
// run-based segment aggregation into bf16 H (r monotone within a node, so the
// accumulator is 2 registers + flush-on-change) -> barrier-free LDS-free
// dense bf16 MFMA GEMM out = H @ Wstack.

#define FEAT 128
#define NRELM 8
#define SCAN_BLK 1024

typedef __attribute__((ext_vector_type(8))) short short8;
typedef __attribute__((ext_vector_type(8))) __bf16 bf16x8;
typedef __attribute__((ext_vector_type(4))) float f32x4;

__device__ __forceinline__ ushort f2bf(float x) {
    union { float f; unsigned u; } v; v.f = x;
    unsigned r = v.u + 0x7FFFu + ((v.u >> 16) & 1u);   // RNE
    return (ushort)(r >> 16);
}

// ---------------- conversions ----------------
__global__ void cvt_feat_kernel(const float* __restrict__ f,
                                ushort* __restrict__ o, int n8) {
    int i = blockIdx.x * blockDim.x + threadIdx.x;
    if (i >= n8) return;
    const float4* f4 = (const float4*)f;
    float4 a = f4[2 * i], b = f4[2 * i + 1];
    union { ushort u[8]; int4 v; } pk;
    pk.u[0] = f2bf(a.x); pk.u[1] = f2bf(a.y); pk.u[2] = f2bf(a.z); pk.u[3] = f2bf(a.w);
    pk.u[4] = f2bf(b.x); pk.u[5] = f2bf(b.y); pk.u[6] = f2bf(b.z); pk.u[7] = f2bf(b.w);
    ((int4*)o)[i] = pk.v;
}

// W[r][k][n] fp32 -> Wt[n][r*128+k] bf16 (K-stacked, n-major)
__global__ void cvt_w_kernel(const float* __restrict__ w,
                             ushort* __restrict__ wt, int total, int KW) {
    int i = blockIdx.x * blockDim.x + threadIdx.x;
    if (i >= total) return;
    int n = i / KW;
    int rk = i - n * KW;
    int r = rk >> 7, k = rk & 127;
    wt[i] = f2bf(w[(r << 14) + (k << 7) + n]);
}

// ---------------- counting sort by key = dst*R + et ----------------
__global__ void hist_kernel(const int* __restrict__ dst,
                            const int* __restrict__ et, int E, int R,
                            int* __restrict__ cnt) {
    int i = blockIdx.x * blockDim.x + threadIdx.x;
    int stride = gridDim.x * blockDim.x;
    for (; i < E; i += stride) atomicAdd(&cnt[dst[i] * R + et[i]], 1);
}

__global__ void scan1_kernel(const int* __restrict__ cnt, int* __restrict__ bsum) {
    int lane = threadIdx.x;
    int base = blockIdx.x * SCAN_BLK + lane * 16;
    int s = 0;
    #pragma unroll
    for (int i = 0; i < 16; i++) s += cnt[base + i];
    for (int o = 32; o; o >>= 1) s += __shfl_down(s, o, 64);
    if (lane == 0) bsum[blockIdx.x] = s;
}

// parallel exclusive scan of bsum[nb], nb <= 1024, single block
__global__ void scan2_kernel(int* __restrict__ bsum, int nb) {
    __shared__ int tmp[SCAN_BLK];
    int t = threadIdx.x;
    int v = (t < nb) ? bsum[t] : 0;
    tmp[t] = v;
    __syncthreads();
    for (int o = 1; o < SCAN_BLK; o <<= 1) {
        int x = (t >= o) ? tmp[t - o] : 0;
        __syncthreads();
        tmp[t] += x;
        __syncthreads();
    }
    if (t < nb) bsum[t] = tmp[t] - v;   // exclusive
}

__global__ void scan3_kernel(const int* __restrict__ cnt,
                             const int* __restrict__ bsum,
                             int* __restrict__ off, int* __restrict__ cursor) {
    int lane = threadIdx.x;
    int base = blockIdx.x * SCAN_BLK + lane * 16;
    int local[16]; int s = 0;
    #pragma unroll
    for (int i = 0; i < 16; i++) { local[i] = cnt[base + i]; s += local[i]; }
    int x = s;
    for (int o = 1; o < 64; o <<= 1) { int y = __shfl_up(x, o, 64); if (lane >= o) x += y; }
    int run = bsum[blockIdx.x] + x - s;     // exclusive prefix
    #pragma unroll
    for (int i = 0; i < 16; i++) { off[base + i] = run; cursor[base + i] = run; run += local[i]; }
}

// sidx[p] = SRC node of the edge (et is implicit in the key ordering)
__global__ void scatter_kernel(const int* __restrict__ dst,
                               const int* __restrict__ et,
                               const int* __restrict__ src, int E, int R,
                               int* __restrict__ cursor, int* __restrict__ sidx) {
    int i = blockIdx.x * blockDim.x + threadIdx.x;
    int stride = gridDim.x * blockDim.x;
    for (; i < E; i += stride) {
        int p = atomicAdd(&cursor[dst[i] * R + et[i]], 1);
        sidx[p] = src[i];
    }
}

// ---------------- phase 1: per-node segment aggregation ----------------
// one wave per dst node; lane covers feat cols {2*lane, 2*lane+1}
__global__ __launch_bounds__(256)
void phase1_kernel(const float* __restrict__ featf,
                   const ushort* __restrict__ featb, int useBf,
                   const int* __restrict__ sidx, const int* __restrict__ off,
                   ushort* __restrict__ H, int N, int Npad, int R,
                   int rbase, int rcount, int KR) {
    int d = blockIdx.x * 4 + (threadIdx.x >> 6);
    if (d >= Npad) return;
    int lane = threadIdx.x & 63;
    unsigned written = 0;
    float S0 = 0.f, S1 = 0.f;
    int rcur = -1;

    if (d < N) {
        int kbase = d * R + rbase;
        int offv = 0;
        if (lane <= rcount) offv = off[kbase + lane];
        int beg = __shfl(offv, 0, 64);
        int end = __shfl(offv, rcount, 64);
        for (int j0 = beg; j0 < end; j0 += 64) {
            int m = end - j0; if (m > 64) m = 64;
            int sv = 0;
            if (lane < m) sv = sidx[j0 + lane];
            // per-lane relation index of edge (j0+lane): # boundaries crossed
            int rl = 0;
            for (int k = 1; k < rcount; k++)
                rl += ((j0 + lane) >= __shfl(offv, k, 64)) ? 1 : 0;
            for (int j = 0; j < m; j++) {
                int s = __shfl(sv, j, 64);
                int rv = __shfl(rl, j, 64);
                if (rv != rcur) {               // wave-uniform, rare
                    if (rcur >= 0) {
                        unsigned p = (unsigned)f2bf(S0) | ((unsigned)f2bf(S1) << 16);
                        *(unsigned*)((char*)H + ((size_t)d * KR + rcur * FEAT) * 2 + 4 * lane) = p;
                        written |= 1u << rcur;
                    }
                    S0 = 0.f; S1 = 0.f; rcur = rv;
                }
                if (useBf) {
                    unsigned v = *(const unsigned*)((const char*)featb +
                                  (size_t)s * (FEAT * 2) + 4 * lane);
                    S0 += __uint_as_float(v << 16);
                    S1 += __uint_as_float(v & 0xffff0000u);
                } else {
                    float2 f = *(const float2*)(featf + (size_t)s * FEAT + 2 * lane);
                    S0 += f.x; S1 += f.y;
                }
            }
        }
        if (rcur >= 0) {
            unsigned p = (unsigned)f2bf(S0) | ((unsigned)f2bf(S1) << 16);
            *(unsigned*)((char*)H + ((size_t)d * KR + rcur * FEAT) * 2 + 4 * lane) = p;
            written |= 1u << rcur;
        }
    }
    // zero-fill rows with no edges (and all padding rows d >= N)
    for (int r = 0; r < rcount; r++)
        if (!((written >> r) & 1))
            *(unsigned*)((char*)H + ((size_t)d * KR + r * FEAT) * 2 + 4 * lane) = 0u;
}

// ---------------- phase 2: out (+)= H @ Wstack, no LDS, no barriers --------
// 4 waves/block; wave w owns rows [blk*128 + w*32, +32); all waves share B
// fragment addresses (served by L1).
__global__ __launch_bounds__(256)
void phase2_kernel(const ushort* __restrict__ H, const ushort* __restrict__ wtb,
                   float* __restrict__ out, int N, int KR, int KW, int kbase,
                   int accum) {
    int t = threadIdx.x, wid = t >> 6, lane = t & 63;
    int lm = lane & 15, lq = lane >> 4;
    int row0 = blockIdx.x * 128 + wid * 32;

    f32x4 acc[16];
    #pragma unroll
    for (int i = 0; i < 16; i++) acc[i] = (f32x4){0.f, 0.f, 0.f, 0.f};

    const ushort* a0p = H + (size_t)(row0 + lm) * KR;
    const ushort* a1p = H + (size_t)(row0 + 16 + lm) * KR;
    const ushort* bp = wtb + (size_t)lm * KW + kbase;

    #pragma unroll 2
    for (int kc = 0; kc < KR; kc += 32) {
        int kof = kc + lq * 8;
        short8 a0 = *(const short8*)(a0p + kof);
        short8 a1 = *(const short8*)(a1p + kof);
        short8 b[8];
        #pragma unroll
        for (int tn = 0; tn < 8; tn++)
            b[tn] = *(const short8*)(bp + (size_t)tn * 16 * KW + kof);
        #pragma unroll
        for (int tn = 0; tn < 8; tn++) {
            acc[tn] = __builtin_amdgcn_mfma_f32_16x16x32_bf16(
                __builtin_bit_cast(bf16x8, a0), __builtin_bit_cast(bf16x8, b[tn]),
                acc[tn], 0, 0, 0);
            acc[8 + tn] = __builtin_amdgcn_mfma_f32_16x16x32_bf16(
                __builtin_bit_cast(bf16x8, a1), __builtin_bit_cast(bf16x8, b[tn]),
                acc[8 + tn], 0, 0, 0);
        }
    }

    #pragma unroll
    for (int tm = 0; tm < 2; tm++) {
        #pragma unroll
        for (int i = 0; i < 4; i++) {
            int row = row0 + tm * 16 + lq * 4 + i;
            if (row < N) {
                float* op = out + (size_t)row * FEAT + lm;
                if (accum) {
                    #pragma unroll
                    for (int tn = 0; tn < 8; tn++) op[tn * 16] += acc[tm * 8 + tn][i];
                } else {
                    #pragma unroll
                    for (int tn = 0; tn < 8; tn++) op[tn * 16] = acc[tm * 8 + tn][i];
                }
            }
        }
    }
}

static inline size_t al256(size_t x) { return (x + 255) & ~(size_t)255; }

extern "C" void kernel_launch(void* const* d_in, const int* in_sizes, int n_in,
                              void* d_out, int out_size, void* d_ws,
                              size_t ws_size, hipStream_t stream) {
    const float* feat = (const float*)d_in[0];
    const float* weight = (const float*)d_in[1];
    const int* src = (const int*)d_in[2];
    const int* dst = (const int*)d_in[3];
    const int* et = (const int*)d_in[4];

    int nfeat = in_sizes[0];
    int N = nfeat / FEAT;                    // 100000
    int R = in_sizes[1] / (FEAT * FEAT);     // 8
    int E = in_sizes[2];                     // 1.6M
    int Npad = ((N + 127) / 128) * 128;      // 100096
    int KW = R * FEAT;                       // 1024
    float* out = (float*)d_out;

    int nkeys_raw = N * R + 1;
    int KEYS = ((nkeys_raw + SCAN_BLK - 1) / SCAN_BLK) * SCAN_BLK;  // 800768
    int nb = KEYS / SCAN_BLK;                // 782 (must be <= 1024)

    // ---- workspace layout ----
    char* ws = (char*)d_ws;
    size_t o = 0;
    size_t cnt_o  = o; o += al256((size_t)KEYS * 4);
    size_t bsum_o = o; o += al256((size_t)SCAN_BLK * 4);
    size_t off_o  = o; o += al256((size_t)KEYS * 4);
    size_t cur_o  = o; o += al256((size_t)KEYS * 4);
    size_t sidx_o = o; o += al256((size_t)E * 4);
    size_t wtb_o  = o; o += al256((size_t)R * FEAT * FEAT * 2);
    size_t base_o = o;

    // pick (relation-split, bf16-gather) so the footprint fits ws
    int RS = 8, useBf = 0;
    const int cand_rs[5] = {1, 2, 4, 4, 8};
    const int cand_bf[5] = {1, 1, 1, 0, 0};
    for (int c = 0; c < 5; c++) {
        size_t need = base_o
                    + (cand_bf[c] ? al256((size_t)nfeat * 2) : 0)
                    + al256((size_t)Npad * (size_t)(KW / cand_rs[c]) * 2);
        if (need <= ws_size) { RS = cand_rs[c]; useBf = cand_bf[c]; break; }
    }
    int RC = R / RS;                         // relations per pass
    int KR = RC * FEAT;                      // K per pass
    size_t featb_o = base_o;
    size_t H_o = base_o + (useBf ? al256((size_t)nfeat * 2) : 0);

    int* cnt    = (int*)(ws + cnt_o);
    int* bsum   = (int*)(ws + bsum_o);
    int* off    = (int*)(ws + off_o);
    int* cursor = (int*)(ws + cur_o);
    int* sidx   = (int*)(ws + sidx_o);
    ushort* wtb   = (ushort*)(ws + wtb_o);
    ushort* featb = (ushort*)(ws + featb_o);
    ushort* H     = (ushort*)(ws + H_o);

    hipMemsetAsync(cnt, 0, (size_t)KEYS * 4, stream);

    int wtotal = R * FEAT * FEAT;
    cvt_w_kernel<<<(wtotal + 255) / 256, 256, 0, stream>>>(weight, wtb, wtotal, KW);
    if (useBf) {
        int n8 = nfeat / 8;
        cvt_feat_kernel<<<(n8 + 255) / 256, 256, 0, stream>>>(feat, featb, n8);
    }
    hist_kernel<<<512, 256, 0, stream>>>(dst, et, E, R, cnt);
    scan1_kernel<<<nb, 64, 0, stream>>>(cnt, bsum);
    scan2_kernel<<<1, SCAN_BLK, 0, stream>>>(bsum, nb);
    scan3_kernel<<<nb, 64, 0, stream>>>(cnt, bsum, off, cursor);
    scatter_kernel<<<512, 256, 0, stream>>>(dst, et, src, E, R, cursor, sidx);

    for (int p = 0; p < RS; p++) {
        phase1_kernel<<<Npad / 4, 256, 0, stream>>>(
            feat, featb, useBf, sidx, off, H, N, Npad, R,
            p * RC, RC, KR);
        phase2_kernel<<<Npad / 128, 256, 0, stream>>>(
            H, wtb, out, N, KR, KW, p * KR, p > 0 ? 1 : 0);
    }
}

// Round 4
// 523.544 us; speedup vs baseline: 1.5174x; 1.1300x over previous
//
#include <hip/hip_runtime.h>
#include <hip/hip_bf16.h>

// RGCN segment MM, fully fused aggregate-then-GEMM:
//   out[d] = sum_r ( sum_{e: dst=d, et=r} feat[src[e]] ) @ W[r]
// Counting-sort edges by key = dst*R + et (sidx stores SRC ids). Main kernel:
// per 128-node block, loop r: gather+sum S_r tile into LDS (bf16), MFMA with
// W[r] into resident fp32 accumulators, store out once. No H intermediate.

#define FEAT 128
#define SCAN_BLK 1024
#define LDKB 136   // LDS row stride (bf16 elems): 128 + 8 pad

typedef __attribute__((ext_vector_type(8))) short short8;
typedef __attribute__((ext_vector_type(8))) __bf16 bf16x8;
typedef __attribute__((ext_vector_type(4))) float f32x4;

__device__ __forceinline__ unsigned f2bf(float x) {
    union { float f; unsigned u; } v; v.f = x;
    unsigned r = v.u + 0x7FFFu + ((v.u >> 16) & 1u);   // RNE
    return r >> 16;
}

// ---------------- conversions ----------------
__global__ void cvt_feat_kernel(const float* __restrict__ f,
                                ushort* __restrict__ o, int n8) {
    int i = blockIdx.x * blockDim.x + threadIdx.x;
    if (i >= n8) return;
    const float4* f4 = (const float4*)f;
    float4 a = f4[2 * i], b = f4[2 * i + 1];
    union { ushort u[8]; int4 v; } pk;
    pk.u[0] = f2bf(a.x); pk.u[1] = f2bf(a.y); pk.u[2] = f2bf(a.z); pk.u[3] = f2bf(a.w);
    pk.u[4] = f2bf(b.x); pk.u[5] = f2bf(b.y); pk.u[6] = f2bf(b.z); pk.u[7] = f2bf(b.w);
    ((int4*)o)[i] = pk.v;
}

// W[r][k][n] fp32 -> Wt[n][r*128+k] bf16 (K-stacked, n-major)
__global__ void cvt_w_kernel(const float* __restrict__ w,
                             ushort* __restrict__ wt, int total, int KW) {
    int i = blockIdx.x * blockDim.x + threadIdx.x;
    if (i >= total) return;
    int n = i / KW;
    int rk = i - n * KW;
    int r = rk >> 7, k = rk & 127;
    wt[i] = (ushort)f2bf(w[(r << 14) + (k << 7) + n]);
}

// ---------------- counting sort by key = dst*R + et ----------------
__global__ void hist_kernel(const int* __restrict__ dst,
                            const int* __restrict__ et, int E, int R,
                            int* __restrict__ cnt) {
    int i = blockIdx.x * blockDim.x + threadIdx.x;
    int stride = gridDim.x * blockDim.x;
    for (; i < E; i += stride) atomicAdd(&cnt[dst[i] * R + et[i]], 1);
}

__global__ void scan1_kernel(const int* __restrict__ cnt, int* __restrict__ bsum) {
    int lane = threadIdx.x;
    int base = blockIdx.x * SCAN_BLK + lane * 16;
    int s = 0;
    #pragma unroll
    for (int i = 0; i < 16; i++) s += cnt[base + i];
    for (int o = 32; o; o >>= 1) s += __shfl_down(s, o, 64);
    if (lane == 0) bsum[blockIdx.x] = s;
}

// parallel exclusive scan of bsum[nb], nb <= 1024, single block
__global__ void scan2_kernel(int* __restrict__ bsum, int nb) {
    __shared__ int tmp[SCAN_BLK];
    int t = threadIdx.x;
    int v = (t < nb) ? bsum[t] : 0;
    tmp[t] = v;
    __syncthreads();
    for (int o = 1; o < SCAN_BLK; o <<= 1) {
        int x = (t >= o) ? tmp[t - o] : 0;
        __syncthreads();
        tmp[t] += x;
        __syncthreads();
    }
    if (t < nb) bsum[t] = tmp[t] - v;   // exclusive
}

__global__ void scan3_kernel(const int* __restrict__ cnt,
                             const int* __restrict__ bsum,
                             int* __restrict__ off, int* __restrict__ cursor) {
    int lane = threadIdx.x;
    int base = blockIdx.x * SCAN_BLK + lane * 16;
    int local[16]; int s = 0;
    #pragma unroll
    for (int i = 0; i < 16; i++) { local[i] = cnt[base + i]; s += local[i]; }
    int x = s;
    for (int o = 1; o < 64; o <<= 1) { int y = __shfl_up(x, o, 64); if (lane >= o) x += y; }
    int run = bsum[blockIdx.x] + x - s;     // exclusive prefix
    #pragma unroll
    for (int i = 0; i < 16; i++) { off[base + i] = run; cursor[base + i] = run; run += local[i]; }
}

// sidx[p] = SRC node id of the edge (et/dst implicit in key ordering)
__global__ void scatter_kernel(const int* __restrict__ dst,
                               const int* __restrict__ et,
                               const int* __restrict__ src, int E, int R,
                               int* __restrict__ cursor, int* __restrict__ sidx) {
    int i = blockIdx.x * blockDim.x + threadIdx.x;
    int stride = gridDim.x * blockDim.x;
    for (; i < E; i += stride) {
        int p = atomicAdd(&cursor[dst[i] * R + et[i]], 1);
        sidx[p] = src[i];
    }
}

// ---------------- fused aggregate + GEMM ----------------
// Block = 128 dst nodes, 4 waves. Per relation r: 16 slots (wave w, quad eq)
// each aggregate one node's segment with 16 B/lane gathers into fp32 regs,
// store bf16 row to LDS; then 128x128x128 MFMA with W[r] into resident acc.
__global__ __launch_bounds__(256, 3)
void fused_kernel(const ushort* __restrict__ featb,
                  const ushort* __restrict__ wtb,
                  const int* __restrict__ sidx, const int* __restrict__ off,
                  float* __restrict__ out, int N, int R, int KW) {
    __shared__ __align__(16) ushort Ssm[128 * LDKB];   // 34816 B
    int t = threadIdx.x, wid = t >> 6, lane = t & 63;
    int eq = lane >> 4, c = lane & 15;     // quad / col-lane (aggregation)
    int lm = lane & 15, lq = lane >> 4;    // MFMA fragment coords
    int base = blockIdx.x * 128;
    int mq = (wid >> 1) * 64, nq = (wid & 1) * 64;

    f32x4 acc[16];
    #pragma unroll
    for (int i = 0; i < 16; i++) acc[i] = (f32x4){0.f, 0.f, 0.f, 0.f};

    for (int r = 0; r < R; r++) {
        // ---- aggregate S_r (128 nodes x 128 cols) into LDS ----
        #pragma unroll 2
        for (int g = 0; g < 8; g++) {
            int dl = g * 16 + wid * 4 + eq;
            int d = base + dl;
            int beg = 0, end = 0;
            if (d < N) {
                beg = off[d * R + r];
                end = off[d * R + r + 1];
            }
            float a[8];
            #pragma unroll
            for (int i = 0; i < 8; i++) a[i] = 0.f;
            for (int pos = beg; pos < end; pos += 4) {
                int sv[4];
                #pragma unroll
                for (int jj = 0; jj < 4; jj++) {
                    int p = pos + jj;
                    sv[jj] = (p < end) ? sidx[p] : -1;
                }
                #pragma unroll
                for (int jj = 0; jj < 4; jj++) {
                    if (sv[jj] >= 0) {
                        uint4 v = *(const uint4*)(featb + (size_t)sv[jj] * FEAT + c * 8);
                        a[0] += __uint_as_float(v.x << 16);
                        a[1] += __uint_as_float(v.x & 0xffff0000u);
                        a[2] += __uint_as_float(v.y << 16);
                        a[3] += __uint_as_float(v.y & 0xffff0000u);
                        a[4] += __uint_as_float(v.z << 16);
                        a[5] += __uint_as_float(v.z & 0xffff0000u);
                        a[6] += __uint_as_float(v.w << 16);
                        a[7] += __uint_as_float(v.w & 0xffff0000u);
                    }
                }
            }
            uint4 pk;
            pk.x = f2bf(a[0]) | (f2bf(a[1]) << 16);
            pk.y = f2bf(a[2]) | (f2bf(a[3]) << 16);
            pk.z = f2bf(a[4]) | (f2bf(a[5]) << 16);
            pk.w = f2bf(a[6]) | (f2bf(a[7]) << 16);
            *(uint4*)&Ssm[dl * LDKB + c * 8] = pk;
        }
        __syncthreads();

        // ---- acc += S_r @ W[r]  (B fragments direct from global, L2-hot) ----
        const ushort* bp = wtb + (size_t)(nq + lm) * KW + r * FEAT;
        #pragma unroll
        for (int ks = 0; ks < 4; ks++) {
            int kof = ks * 32 + lq * 8;
            short8 af[4], bfg[4];
            #pragma unroll
            for (int tm = 0; tm < 4; tm++)
                af[tm] = *(const short8*)&Ssm[(mq + tm * 16 + lm) * LDKB + kof];
            #pragma unroll
            for (int tn = 0; tn < 4; tn++)
                bfg[tn] = *(const short8*)(bp + (size_t)(tn * 16) * KW + kof);
            #pragma unroll
            for (int tm = 0; tm < 4; tm++)
                #pragma unroll
                for (int tn = 0; tn < 4; tn++)
                    acc[tm * 4 + tn] = __builtin_amdgcn_mfma_f32_16x16x32_bf16(
                        __builtin_bit_cast(bf16x8, af[tm]),
                        __builtin_bit_cast(bf16x8, bfg[tn]),
                        acc[tm * 4 + tn], 0, 0, 0);
        }
        __syncthreads();
    }

    // ---- epilogue: single store of the 128x128 out tile ----
    #pragma unroll
    for (int tm = 0; tm < 4; tm++) {
        #pragma unroll
        for (int i = 0; i < 4; i++) {
            int row = base + mq + tm * 16 + lq * 4 + i;
            if (row < N) {
                float* op = out + (size_t)row * FEAT + nq + lm;
                #pragma unroll
                for (int tn = 0; tn < 4; tn++) op[tn * 16] = acc[tm * 4 + tn][i];
            }
        }
    }
}

static inline size_t al256(size_t x) { return (x + 255) & ~(size_t)255; }

extern "C" void kernel_launch(void* const* d_in, const int* in_sizes, int n_in,
                              void* d_out, int out_size, void* d_ws,
                              size_t ws_size, hipStream_t stream) {
    const float* feat = (const float*)d_in[0];
    const float* weight = (const float*)d_in[1];
    const int* src = (const int*)d_in[2];
    const int* dst = (const int*)d_in[3];
    const int* et = (const int*)d_in[4];

    int nfeat = in_sizes[0];
    int N = nfeat / FEAT;                    // 100000
    int R = in_sizes[1] / (FEAT * FEAT);     // 8
    int E = in_sizes[2];                     // 1.6M
    int Npad = ((N + 127) / 128) * 128;      // 100096
    int KW = R * FEAT;                       // 1024
    float* out = (float*)d_out;

    int nkeys_raw = N * R + 1;
    int KEYS = ((nkeys_raw + SCAN_BLK - 1) / SCAN_BLK) * SCAN_BLK;  // 800768
    int nb = KEYS / SCAN_BLK;                // 782 (<= 1024)

    // ---- workspace layout (~44 MB total) ----
    char* ws = (char*)d_ws;
    size_t o = 0;
    size_t cnt_o  = o; o += al256((size_t)KEYS * 4);
    size_t bsum_o = o; o += al256((size_t)SCAN_BLK * 4);
    size_t off_o  = o; o += al256((size_t)KEYS * 4);
    size_t cur_o  = o; o += al256((size_t)KEYS * 4);
    size_t sidx_o = o; o += al256((size_t)E * 4);
    size_t wtb_o  = o; o += al256((size_t)R * FEAT * FEAT * 2);
    size_t featb_o = o;

    int* cnt    = (int*)(ws + cnt_o);
    int* bsum   = (int*)(ws + bsum_o);
    int* off    = (int*)(ws + off_o);
    int* cursor = (int*)(ws + cur_o);
    int* sidx   = (int*)(ws + sidx_o);
    ushort* wtb   = (ushort*)(ws + wtb_o);
    ushort* featb = (ushort*)(ws + featb_o);

    hipMemsetAsync(cnt, 0, (size_t)KEYS * 4, stream);

    int wtotal = R * FEAT * FEAT;
    cvt_w_kernel<<<(wtotal + 255) / 256, 256, 0, stream>>>(weight, wtb, wtotal, KW);
    int n8 = nfeat / 8;
    cvt_feat_kernel<<<(n8 + 255) / 256, 256, 0, stream>>>(feat, featb, n8);

    hist_kernel<<<784, 256, 0, stream>>>(dst, et, E, R, cnt);
    scan1_kernel<<<nb, 64, 0, stream>>>(cnt, bsum);
    scan2_kernel<<<1, SCAN_BLK, 0, stream>>>(bsum, nb);
    scan3_kernel<<<nb, 64, 0, stream>>>(cnt, bsum, off, cursor);
    scatter_kernel<<<784, 256, 0, stream>>>(dst, et, src, E, R, cursor, sidx);

    fused_kernel<<<Npad / 128, 256, 0, stream>>>(featb, wtb, sidx, off,
                                                 out, N, R, KW);
}